// Round 4
// baseline (312.793 us; speedup 1.0000x reference)
//
#include <hip/hip_runtime.h>

// B-spline basis (Cox-de Boor), degree 3, 256 knots, 252 basis fns, N=1M.
// Round-4: only 2 of 63 float4 chunks per row are nonzero, so:
//   phase 1 : per-thread (row = base+tid) Cox-de Boor -> band in REGISTERS
//   phase 2a: pure zero-stream of the block tile (fillBuffer-clone: no LDS,
//             no selects, 4x16B contiguous per thread per iteration)
//   phase 2b: after __syncthreads (vmcnt(0) drain -> WAW ordered), each
//             thread overwrites its own row's <=2 band chunks from registers.
// Round-3 was 5.3 TB/s vs the 6.5 TB/s in-situ fill ceiling because phase 2
// paid ~3 LDS reads + ~12 VALU per 16B store; this removes all of it.

constexpr int NUM_KNOTS = 256;
constexpr int NUM_BASIS = 252;       // NUM_KNOTS - DEGREE - 1
constexpr int CHUNKS    = 63;        // float4 chunks per row (1008 B)
constexpr int ROWS      = 256;       // rows per block == blockDim.x
constexpr int TILE_F4   = ROWS * CHUNKS;   // 16128 float4 per block tile

typedef float f4 __attribute__((ext_vector_type(4)));

__global__ __launch_bounds__(256) void bspline_kernel(
    const float* __restrict__ X, const float* __restrict__ knots,
    float* __restrict__ out, int n)
{
    __shared__ float s_knots[NUM_KNOTS];

    const int tid  = threadIdx.x;
    const int base = blockIdx.x * ROWS;
    const int row  = base + tid;

    s_knots[tid] = knots[tid];
    __syncthreads();

    // ---------- phase 1: per-row Cox-de Boor -> band in registers ----------
    float x    = X[min(row, n - 1)];
    float k0   = s_knots[0];
    float kend = s_knots[NUM_KNOTS - 1];
    float inv_h = (float)(NUM_KNOTS - 1) / (kend - k0);

    int j0 = (int)floorf((x - k0) * inv_h);
    j0 = min(max(j0, 0), NUM_KNOTS - 2);
    while (j0 > 0 && x < s_knots[j0]) --j0;
    while (j0 < NUM_KNOTS - 2 && x >= s_knots[j0 + 1]) ++j0;

    // cb[i] at level k holds B_{j0-k+i, k}; level 0: B_{j0,0} = 1
    float cb[4] = {1.0f, 0.0f, 0.0f, 0.0f};
    #pragma unroll
    for (int k = 1; k <= 3; ++k) {
        #pragma unroll
        for (int i = 3; i >= 0; --i) {           // downward: in-place safe
            if (i > k) continue;
            int j = j0 - k + i;
            float plo = (i >= 1)     ? cb[i - 1] : 0.0f;  // B_{j,  k-1}
            float phi = (i <= k - 1) ? cb[i]     : 0.0f;  // B_{j+1,k-1}
            float val = 0.0f;
            // reference truncation: level-k entries valid for j in [0, 254-k]
            if (j >= 0 && j <= NUM_KNOTS - 2 - k) {
                float kj  = s_knots[j];
                float kj1 = s_knots[j + 1];
                float kjk = s_knots[j + k];
                float kk1 = s_knots[j + k + 1];
                val = (x - kj) / (kjk - kj) * plo
                    + (kk1 - x) / (kk1 - kj1) * phi;
            }
            cb[i] = val;
        }
    }

    // Band cols j0-3..j0 -> two aligned float4 chunks clo=(j0-3)>>2, clo+1,
    // split at a=(j0-3)&3 via conditional register shifts (static idx only).
    int s = j0 - 3;                  // in [-3, 251]
    int a = s & 3;
    int clo = s >> 2;                // arithmetic shift: -3..-1 -> -1
    float lo0=cb[0], lo1=cb[1], lo2=cb[2], lo3=cb[3];
    float hi0=0.f, hi1=0.f, hi2=0.f, hi3=0.f;
    if (a & 2) { hi3=hi1; hi2=hi0; hi1=lo3; hi0=lo2;
                 lo3=lo1; lo2=lo0; lo1=0.f; lo0=0.f; }
    if (a & 1) { hi3=hi2; hi2=hi1; hi1=hi0; hi0=lo3;
                 lo3=lo2; lo2=lo1; lo1=lo0; lo0=0.f; }
    f4 vlo; vlo.x=lo0; vlo.y=lo1; vlo.z=lo2; vlo.w=lo3;
    f4 vhi; vhi.x=hi0; vhi.y=hi1; vhi.z=hi2; vhi.w=hi3;
    // clo == -1 (j0<=2): lower spill is out of range, valid part is in vhi
    // at chunk 0. clo == 62 (j0==254): vhi (cols 252..254) is truncated away.

    // ---------- phase 2a: zero-stream the block tile (fillBuffer clone) ----
    f4 z = (f4)0.0f;
    f4* tile = (f4*)(out + (size_t)base * NUM_BASIS);
    const bool full = (base + ROWS <= n);        // true for N = 1M
    if (full) {
        f4* dst = tile + tid * 4;
        #pragma unroll
        for (int it = 0; it < 15; ++it) {        // 15*1024 = 15360 f4
            dst[0] = z; dst[1] = z; dst[2] = z; dst[3] = z;  // 64B contiguous
            dst += 1024;                          // 256 threads * 4 f4
        }
        if (tid < (TILE_F4 - 15 * 1024) / 4) {   // remainder: 192 threads
            f4* d2 = tile + 15 * 1024 + tid * 4;
            d2[0] = z; d2[1] = z; d2[2] = z; d2[3] = z;
        }
    } else {
        int lim = (n - base) * CHUNKS;
        for (int i = tid; i < lim; i += 256) tile[i] = z;
    }
    __syncthreads();   // vmcnt(0)+barrier: all zero stores ordered before 2b

    // ---------- phase 2b: band overwrite from registers ----------
    if (row < n) {
        f4* rowp = (f4*)(out + (size_t)row * NUM_BASIS);
        if (clo >= 0)         rowp[clo]     = vlo;
        if (clo < CHUNKS - 1) rowp[clo + 1] = vhi;
    }
}

extern "C" void kernel_launch(void* const* d_in, const int* in_sizes, int n_in,
                              void* d_out, int out_size, void* d_ws, size_t ws_size,
                              hipStream_t stream) {
    const float* x     = (const float*)d_in[0];
    const float* knots = (const float*)d_in[1];
    float* out = (float*)d_out;
    int n = in_sizes[0];
    int grid = (n + ROWS - 1) / ROWS;
    bspline_kernel<<<grid, 256, 0, stream>>>(x, knots, out, n);
}

// Round 5
// 227.513 us; speedup vs baseline: 1.3748x; 1.3748x over previous
//
#include <hip/hip_runtime.h>

// B-spline basis (Cox-de Boor), degree 3, 256 knots, 252 basis fns, N=1M.
// Round-5: persistent blocks, 32-row tile image in LDS.
//   - LDS image zeroed ONCE per block; per tile only the <=2 band chunks per
//     row are cleared (previous) and written (new) -> zero-fill amortized away.
//   - Stream phase is a fill-clone: ds_read_b128 + global_store_dwordx4,
//     no selects, no per-store branches, every HBM line touched exactly once.
// Round-4's two-pass failed (313us) because zero-lines were evicted from L2
// before the band overwrite (RMW + double writeback). Round-3 (203us,
// 5.3 TB/s vs 6.8 TB/s in-situ fill ceiling) paid ~17 instr + 3 LDS-dep
// reads per 16B store; this drops it to ~3 instr per 16B.

constexpr int NUM_KNOTS = 256;
constexpr int NUM_BASIS = 252;       // NUM_KNOTS - DEGREE - 1
constexpr int CHUNKS    = 63;        // float4 chunks per row (1008 B)
constexpr int TROWS     = 32;        // rows per tile
constexpr int TILE_F4   = TROWS * CHUNKS;   // 2016 f4 = 31.5 KB
constexpr int BLOCK     = 256;

typedef float f4 __attribute__((ext_vector_type(4)));

__global__ __launch_bounds__(BLOCK) void bspline_kernel(
    const float* __restrict__ X, const float* __restrict__ knots,
    float* __restrict__ out, int n, int ntiles)
{
    __shared__ float s_knots[NUM_KNOTS];
    __shared__ f4    s_img[TILE_F4];         // 32 rows x 63 chunks, row-major

    const int tid = threadIdx.x;
    s_knots[tid] = knots[tid];
    for (int i = tid; i < TILE_F4; i += BLOCK) s_img[i] = (f4)0.0f;
    __syncthreads();

    int  prev_clo   = 0;
    bool prev_valid = false;                  // per band-thread (tid < TROWS)

    for (int tile = blockIdx.x; tile < ntiles; tile += gridDim.x) {
        const int tbase = tile * TROWS;

        // ---- phase 1 (threads 0..31): band for row tbase+tid -> LDS image ----
        if (tid < TROWS) {
            const int row = tbase + tid;
            float x    = X[min(row, n - 1)];
            float k0   = s_knots[0];
            float kend = s_knots[NUM_KNOTS - 1];
            float inv_h = (float)(NUM_KNOTS - 1) / (kend - k0);

            int j0 = (int)floorf((x - k0) * inv_h);
            j0 = min(max(j0, 0), NUM_KNOTS - 2);
            while (j0 > 0 && x < s_knots[j0]) --j0;
            while (j0 < NUM_KNOTS - 2 && x >= s_knots[j0 + 1]) ++j0;

            // cb[i] at level k holds B_{j0-k+i, k}; level 0: B_{j0,0} = 1
            float cb[4] = {1.0f, 0.0f, 0.0f, 0.0f};
            #pragma unroll
            for (int k = 1; k <= 3; ++k) {
                #pragma unroll
                for (int i = 3; i >= 0; --i) {       // downward: in-place safe
                    if (i > k) continue;
                    int j = j0 - k + i;
                    float plo = (i >= 1)     ? cb[i - 1] : 0.0f;  // B_{j,  k-1}
                    float phi = (i <= k - 1) ? cb[i]     : 0.0f;  // B_{j+1,k-1}
                    float val = 0.0f;
                    // reference truncation: level-k valid for j in [0, 254-k]
                    if (j >= 0 && j <= NUM_KNOTS - 2 - k) {
                        float kj  = s_knots[j];
                        float kj1 = s_knots[j + 1];
                        float kjk = s_knots[j + k];
                        float kk1 = s_knots[j + k + 1];
                        val = (x - kj) / (kjk - kj) * plo
                            + (kk1 - x) / (kk1 - kj1) * phi;
                    }
                    cb[i] = val;
                }
            }

            // Band cols j0-3..j0 -> aligned chunks clo=(j0-3)>>2 and clo+1,
            // split at a=(j0-3)&3 via conditional register shifts.
            int s = j0 - 3;                  // in [-3, 251]
            int a = s & 3;
            int clo = s >> 2;                // -3..-1 -> -1 (arith shift)
            float lo0=cb[0], lo1=cb[1], lo2=cb[2], lo3=cb[3];
            float hi0=0.f, hi1=0.f, hi2=0.f, hi3=0.f;
            if (a & 2) { hi3=hi1; hi2=hi0; hi1=lo3; hi0=lo2;
                         lo3=lo1; lo2=lo0; lo1=0.f; lo0=0.f; }
            if (a & 1) { hi3=hi2; hi2=hi1; hi1=hi0; hi0=lo3;
                         lo3=lo2; lo2=lo1; lo1=lo0; lo0=0.f; }
            f4 vlo; vlo.x=lo0; vlo.y=lo1; vlo.z=lo2; vlo.w=lo3;
            f4 vhi; vhi.x=hi0; vhi.y=hi1; vhi.z=hi2; vhi.w=hi3;

            f4* rowimg = s_img + tid * CHUNKS;
            f4  z = (f4)0.0f;
            if (prev_valid) {                       // clear last tile's band
                if (prev_clo >= 0)          rowimg[prev_clo]     = z;
                if (prev_clo < CHUNKS - 1)  rowimg[prev_clo + 1] = z;
            }
            if (row < n) {
                if (clo >= 0)          rowimg[clo]     = vlo;
                if (clo < CHUNKS - 1)  rowimg[clo + 1] = vhi;
                prev_clo = clo; prev_valid = true;
            } else {
                prev_valid = false;
            }
        }
        __syncthreads();

        // ---- phase 2: stream LDS image -> HBM (fill-clone inner loop) ----
        f4* dst = (f4*)out + (size_t)tbase * CHUNKS;
        if (tbase + TROWS <= n) {                   // full tile (always, N=1M)
            #pragma unroll
            for (int i = 0; i < 7; ++i)             // 7*256 = 1792
                dst[tid + 256 * i] = s_img[tid + 256 * i];
            if (tid < TILE_F4 - 7 * 256)            // remainder: 224 threads
                dst[tid + 7 * 256] = s_img[tid + 7 * 256];
        } else {                                    // tail tile
            int lim = (n - tbase) * CHUNKS;
            for (int i = tid; i < lim; i += BLOCK) dst[i] = s_img[i];
        }
        __syncthreads();   // all lanes done reading image before next update
    }
}

extern "C" void kernel_launch(void* const* d_in, const int* in_sizes, int n_in,
                              void* d_out, int out_size, void* d_ws, size_t ws_size,
                              hipStream_t stream) {
    const float* x     = (const float*)d_in[0];
    const float* knots = (const float*)d_in[1];
    float* out = (float*)d_out;
    int n = in_sizes[0];
    int ntiles = (n + TROWS - 1) / TROWS;           // 32768 for N=1M
    int grid = 1024;                                 // 4 blocks/CU x 256 CU
    if (grid > ntiles) grid = ntiles;
    bspline_kernel<<<grid, BLOCK, 0, stream>>>(x, knots, out, n, ntiles);
}